// Round 2
// baseline (966.595 us; speedup 1.0000x reference)
//
#include <hip/hip_runtime.h>
#include <stdint.h>

#define HID   1024
#define INTER 2048
#define NQK   4096
#define STATE 64
#define BSZ   4
#define LEN   4096
#define RTOT  (BSZ*LEN)
#define NCAT  2176
#define LC    128
#define NCH   (LEN/LC)

typedef unsigned short u16;
typedef u16   u16x4 __attribute__((ext_vector_type(4)));
typedef u16   u16x8 __attribute__((ext_vector_type(8)));
typedef float f32x4 __attribute__((ext_vector_type(4)));

__device__ __forceinline__ u16 f2bf(float f) {
  uint32_t u = __float_as_uint(f);
  u += 0x7fffu + ((u >> 16) & 1u);
  return (u16)(u >> 16);
}
__device__ __forceinline__ float bf2f(u16 h) {
  return __uint_as_float(((uint32_t)h) << 16);
}

typedef __attribute__((address_space(1))) void gvoid;
typedef __attribute__((address_space(3))) void lvoid;
__device__ __forceinline__ void gload16(const void* g, void* l) {
  __builtin_amdgcn_global_load_lds((gvoid*)(uintptr_t)g, (lvoid*)l, 16, 0, 0);
}

__device__ __forceinline__ void mfma16(f32x4 a, f32x4 b, f32x4& c) {
  asm volatile("v_mfma_f32_16x16x32_bf16 %0, %1, %2, %0" : "+v"(c) : "v"(a), "v"(b));
}

// ---------------- weight transpose+convert: src [K][N] f32 -> dst [N][K] bf16
__global__ __launch_bounds__(256) void wconvT_kernel(const float* __restrict__ src,
                                                     u16* __restrict__ dst, int K, int N) {
  __shared__ float t[32][33];
  int tx = threadIdx.x & 31, ty = threadIdx.x >> 5;
  int n0 = blockIdx.x * 32, k0 = blockIdx.y * 32;
#pragma unroll
  for (int i = 0; i < 4; ++i)
    t[ty + 8*i][tx] = src[(size_t)(k0 + ty + 8*i) * N + n0 + tx];
  __syncthreads();
#pragma unroll
  for (int i = 0; i < 4; ++i)
    dst[(size_t)(n0 + ty + 8*i) * K + k0 + tx] = f2bf(t[tx][ty + 8*i]);
}

__global__ void bcat_kernel(const float* b_dt, const float* dt_bias, const float* b_B,
                            const float* b_C, float* bcat) {
  int i = blockIdx.x * 256 + threadIdx.x;
  if (i >= NCAT) return;
  float v;
  if (i < INTER) v = b_dt[i] + dt_bias[i];
  else if (i < INTER + STATE) v = b_B[i - INTER];
  else v = b_C[i - INTER - STATE];
  bcat[i] = v;
}

// cond[b][j] = condition[b] @ W_cond + b_cond
__global__ __launch_bounds__(256) void cond_kernel(const float* __restrict__ condition,
    const float* __restrict__ W, const float* __restrict__ bias, float* __restrict__ out) {
  int b = blockIdx.y;
  int j = blockIdx.x * 256 + threadIdx.x;
  float acc = bias[j];
  const float* crow = condition + b * HID;
  for (int k = 0; k < HID; ++k)
    acc = fmaf(crow[k], W[(size_t)k * INTER + j], acc);
  out[b * INTER + j] = acc;
}

// LayerNorm: one block per row of 1024
__global__ __launch_bounds__(256) void ln_kernel(const float* __restrict__ x,
    const float* __restrict__ g, const float* __restrict__ bb, u16* __restrict__ xn) {
  int r = blockIdx.x;
  int tid = threadIdx.x;
  const float4 v = ((const float4*)(x + (size_t)r * HID))[tid];
  float s = v.x + v.y + v.z + v.w;
  float sq = v.x*v.x + v.y*v.y + v.z*v.z + v.w*v.w;
  for (int o = 32; o; o >>= 1) { s += __shfl_xor(s, o); sq += __shfl_xor(sq, o); }
  __shared__ float ps[4], pq[4];
  int wid = tid >> 6, lane = tid & 63;
  if (lane == 0) { ps[wid] = s; pq[wid] = sq; }
  __syncthreads();
  s = ps[0] + ps[1] + ps[2] + ps[3];
  sq = pq[0] + pq[1] + pq[2] + pq[3];
  float mu = s * (1.f / HID);
  float var = sq * (1.f / HID) - mu * mu;
  float rstd = rsqrtf(var + 1e-5f);
  int c = tid * 4;
  u16x4 ov;
  ov.x = f2bf((v.x - mu) * rstd * g[c+0] + bb[c+0]);
  ov.y = f2bf((v.y - mu) * rstd * g[c+1] + bb[c+1]);
  ov.z = f2bf((v.z - mu) * rstd * g[c+2] + bb[c+2]);
  ov.w = f2bf((v.w - mu) * rstd * g[c+3] + bb[c+3]);
  *(u16x4*)(xn + (size_t)r * HID + c) = ov;
}

// ---------------- GEMM: C[M,N] = A[M,K](bf16) * Bt[N,K]^T (bf16), fp32 acc.
// 128x128 tile, BK=32, 4 waves in 2x2, each wave 64x64 via 4x4 16x16x32 MFMA.
// EPI 0: +bias, split -> out0 (cols<INTER) / out1 (cols>=INTER), bf16
// EPI 1: dt tiles (col0<INTER): softplus(v+bias) row-reduced -> atomicAdd dtsum
//        B/C tile: v+bias -> Bmat/Cmat f32
// EPI 2: v + bias + resid -> outf (f32)
template<int EPI>
__global__ __launch_bounds__(256) void gemm_bt(
    const u16* __restrict__ A, const u16* __restrict__ Bt, int K,
    const float* __restrict__ bias,
    u16* __restrict__ out0, u16* __restrict__ out1,
    float* __restrict__ dtsum, float* __restrict__ Bmat, float* __restrict__ Cmat,
    const float* __restrict__ resid, float* __restrict__ outf)
{
  __shared__ u16 lA[128 * 32];
  __shared__ u16 lB[128 * 32];
  const int tid = threadIdx.x;
  const int lane = tid & 63;
  const int wid = tid >> 6;
  const int wm = wid >> 1, wn = wid & 1;
  const int lr = lane & 15, lk = lane >> 4;
  const int col0 = blockIdx.x * 128;
  const int row0 = blockIdx.y * 128;
  const int wbase = tid & 192;

  f32x4 acc[4][4];
#pragma unroll
  for (int i = 0; i < 4; ++i)
#pragma unroll
    for (int j = 0; j < 4; ++j) acc[i][j] = (f32x4){0.f, 0.f, 0.f, 0.f};

  const size_t arow = (size_t)row0 * K;
  const size_t brow = (size_t)col0 * K;

  asm volatile("s_nop 7");
  for (int kt = 0; kt < K; kt += 32) {
    __syncthreads();
#pragma unroll
    for (int j = 0; j < 2; ++j) {
      int cbase = j * 256 + wbase;
      int chunk = cbase + lane;
      gload16(A + arow + (size_t)(chunk >> 2) * K + kt + (chunk & 3) * 8, &lA[cbase * 8]);
    }
#pragma unroll
    for (int j = 0; j < 2; ++j) {
      int cbase = j * 256 + wbase;
      int chunk = cbase + lane;
      gload16(Bt + brow + (size_t)(chunk >> 2) * K + kt + (chunk & 3) * 8, &lB[cbase * 8]);
    }
    __syncthreads();
    f32x4 aF[4], bF[4];
#pragma unroll
    for (int f = 0; f < 4; ++f)
      aF[f] = *(const f32x4*)&lA[(wm * 64 + f * 16 + lr) * 32 + lk * 8];
#pragma unroll
    for (int f = 0; f < 4; ++f)
      bF[f] = *(const f32x4*)&lB[(wn * 64 + f * 16 + lr) * 32 + lk * 8];
#pragma unroll
    for (int fm = 0; fm < 4; ++fm)
#pragma unroll
      for (int fn = 0; fn < 4; ++fn)
        mfma16(aF[fm], bF[fn], acc[fm][fn]);
  }
  asm volatile("s_nop 7\n\ts_nop 7\n\ts_nop 7");

  const int rb = row0 + wm * 64;
  const int cb = col0 + wn * 64;

  if constexpr (EPI == 0) {
#pragma unroll
    for (int fm = 0; fm < 4; ++fm)
#pragma unroll
      for (int fn = 0; fn < 4; ++fn)
#pragma unroll
        for (int rr = 0; rr < 4; ++rr) {
          int rowg = rb + fm * 16 + lk * 4 + rr;
          int colg = cb + fn * 16 + lr;
          float v = acc[fm][fn][rr] + bias[colg];
          if (colg < INTER) out0[(size_t)rowg * INTER + colg] = f2bf(v);
          else              out1[(size_t)rowg * INTER + colg - INTER] = f2bf(v);
        }
  } else if constexpr (EPI == 1) {
    if (col0 < INTER) {
#pragma unroll
      for (int fm = 0; fm < 4; ++fm)
#pragma unroll
        for (int rr = 0; rr < 4; ++rr) {
          float s = 0.f;
#pragma unroll
          for (int fn = 0; fn < 4; ++fn) {
            int colg = cb + fn * 16 + lr;
            float v = acc[fm][fn][rr] + bias[colg];
            s += (v > 20.f) ? v : log1pf(expf(v));
          }
#pragma unroll
          for (int o = 1; o < 16; o <<= 1) s += __shfl_xor(s, o);
          if (lr == 0) {
            int rowg = rb + fm * 16 + lk * 4 + rr;
            atomicAdd(&dtsum[rowg], s);
          }
        }
    } else {
#pragma unroll
      for (int fm = 0; fm < 4; ++fm)
#pragma unroll
        for (int fn = 0; fn < 4; ++fn)
#pragma unroll
          for (int rr = 0; rr < 4; ++rr) {
            int rowg = rb + fm * 16 + lk * 4 + rr;
            int colL = wn * 64 + fn * 16 + lr;
            float v = acc[fm][fn][rr] + bias[INTER + colL];
            if (colL < STATE) Bmat[(size_t)rowg * STATE + colL] = v;
            else              Cmat[(size_t)rowg * STATE + colL - STATE] = v;
          }
    }
  } else {
#pragma unroll
    for (int fm = 0; fm < 4; ++fm)
#pragma unroll
      for (int fn = 0; fn < 4; ++fn)
#pragma unroll
        for (int rr = 0; rr < 4; ++rr) {
          int rowg = rb + fm * 16 + lk * 4 + rr;
          int colg = cb + fn * 16 + lr;
          float v = acc[fm][fn][rr] + bias[colg];
          outf[(size_t)rowg * HID + colg] = v + resid[(size_t)rowg * HID + colg];
        }
  }
}

// depthwise conv3 (pad 1) + conv_b + silu + cond add; also row-sum of xp
__global__ __launch_bounds__(256) void conv_kernel(
    const u16* __restrict__ xproj, const float* __restrict__ cw, const float* __restrict__ cbias,
    const float* __restrict__ condv, u16* __restrict__ xp, float* __restrict__ xpsum)
{
  int r = blockIdx.x;
  int b = r >> 12, l = r & (LEN - 1);
  int c0 = threadIdx.x * 8;
  const u16* base = xproj + (size_t)r * INTER + c0;
  u16x8 x0 = *(const u16x8*)base;
  u16x8 xm = (u16x8){0,0,0,0,0,0,0,0};
  u16x8 xpv = (u16x8){0,0,0,0,0,0,0,0};
  if (l > 0)       xm  = *(const u16x8*)(base - INTER);
  if (l < LEN - 1) xpv = *(const u16x8*)(base + INTER);
  float sum = 0.f;
  u16x8 ov;
#pragma unroll
  for (int j = 0; j < 8; ++j) {
    int c = c0 + j;
    float v = cw[c*3+0] * bf2f(xm[j]) + cw[c*3+1] * bf2f(x0[j]) + cw[c*3+2] * bf2f(xpv[j]) + cbias[c];
    float sg = v / (1.f + expf(-v));
    float o = sg + condv[b * INTER + c];
    sum += o;
    ov[j] = f2bf(o);
  }
  *(u16x8*)(xp + (size_t)r * INTER + c0) = ov;
  for (int o = 32; o; o >>= 1) sum += __shfl_xor(sum, o);
  __shared__ float ps[4];
  if ((threadIdx.x & 63) == 0) ps[threadIdx.x >> 6] = sum;
  __syncthreads();
  if (threadIdx.x == 0) xpsum[r] = ps[0] + ps[1] + ps[2] + ps[3];
}

__global__ __launch_bounds__(256) void scanprep_kernel(const float* __restrict__ A_log,
    const float* __restrict__ dtsum, const float* __restrict__ xpsum,
    const float* BmatIn, float* Adisc, float* Bx)
{
  int e = blockIdx.x * 256 + threadIdx.x;
  int r = e >> 6, s = e & 63;
  float dtm = dtsum[r] * (1.f / INTER);
  float xpm = xpsum[r] * (1.f / INTER);
  Adisc[e] = expf(-expf(A_log[s]) * dtm);
  Bx[e] = BmatIn[e] * dtm * xpm;
}

__global__ __launch_bounds__(64) void scanA_kernel(const float* __restrict__ Adisc,
    const float* __restrict__ Bx, float* __restrict__ cA, float* __restrict__ cB)
{
  int g = blockIdx.x; int b = g / NCH, ch = g % NCH;
  int s = threadIdx.x;
  float ap = 1.f, bacc = 0.f;
  size_t base = ((size_t)(b * LEN + ch * LC) << 6) + s;
  for (int i = 0; i < LC; ++i) {
    float a = Adisc[base], bb = Bx[base];
    bacc = fmaf(a, bacc, bb);
    ap *= a;
    base += 64;
  }
  cA[(size_t)g * 64 + s] = ap;
  cB[(size_t)g * 64 + s] = bacc;
}

__global__ __launch_bounds__(256) void scanB_kernel(const float* __restrict__ cA,
    const float* __restrict__ cB, float* __restrict__ hin)
{
  int t = threadIdx.x; int b = t >> 6, s = t & 63;
  float h = 0.f;
  for (int ch = 0; ch < NCH; ++ch) {
    size_t i = (size_t)(b * NCH + ch) * 64 + s;
    hin[i] = h;
    h = fmaf(cA[i], h, cB[i]);
  }
}

__global__ __launch_bounds__(64) void scanC_kernel(const float* __restrict__ Adisc,
    const float* __restrict__ Bx, const float* __restrict__ Cmat,
    const float* __restrict__ hin, float* __restrict__ yvec)
{
  int g = blockIdx.x; int b = g / NCH, ch = g % NCH;
  int s = threadIdx.x;
  float h = hin[(size_t)g * 64 + s];
  int l0 = ch * LC;
  size_t base = ((size_t)(b * LEN + l0) << 6) + s;
  for (int i = 0; i < LC; ++i) {
    h = fmaf(Adisc[base], h, Bx[base]);
    float p = Cmat[base] * h;
    for (int o = 32; o; o >>= 1) p += __shfl_xor(p, o);
    if (s == 0) yvec[b * LEN + l0 + i] = p;
    base += 64;
  }
}

__global__ __launch_bounds__(256) void yin_kernel(const u16* __restrict__ xp,
    const u16* __restrict__ gate, const float* __restrict__ yvec,
    const float* __restrict__ Dp, u16* __restrict__ yin)
{
  int i = blockIdx.x * 256 + threadIdx.x;
  int r = i >> 8;
  int c0 = (i & 255) * 8;
  size_t off = (size_t)r * INTER + c0;
  u16x8 xv = *(const u16x8*)(xp + off);
  u16x8 gv = *(const u16x8*)(gate + off);
  float yv = yvec[r];
  u16x8 ov;
#pragma unroll
  for (int j = 0; j < 8; ++j) {
    float g = bf2f(gv[j]);
    float sg = g / (1.f + expf(-g));
    float val = (yv + bf2f(xv[j]) * Dp[c0 + j]) * sg;
    ov[j] = f2bf(val);
  }
  *(u16x8*)(yin + off) = ov;
}

extern "C" void kernel_launch(void* const* d_in, const int* in_sizes, int n_in,
                              void* d_out, int out_size, void* d_ws, size_t ws_size,
                              hipStream_t stream) {
  (void)in_sizes; (void)n_in; (void)out_size; (void)ws_size;
  const float* x         = (const float*)d_in[0];
  const float* condition = (const float*)d_in[1];
  const float* ln_g      = (const float*)d_in[2];
  const float* ln_b      = (const float*)d_in[3];
  const float* W_in      = (const float*)d_in[4];
  const float* b_in      = (const float*)d_in[5];
  const float* conv_w    = (const float*)d_in[6];
  const float* conv_b    = (const float*)d_in[7];
  const float* W_dt      = (const float*)d_in[8];
  const float* b_dt      = (const float*)d_in[9];
  const float* dt_bias   = (const float*)d_in[10];
  const float* A_log     = (const float*)d_in[11];
  const float* Dp        = (const float*)d_in[12];
  const float* W_B       = (const float*)d_in[13];
  const float* b_B       = (const float*)d_in[14];
  const float* W_C       = (const float*)d_in[15];
  const float* b_C       = (const float*)d_in[16];
  const float* W_cond    = (const float*)d_in[17];
  const float* b_cond    = (const float*)d_in[18];
  const float* W_out     = (const float*)d_in[19];
  const float* b_out     = (const float*)d_in[20];

  char* ws = (char*)d_ws;
  u16*   wt_in  = (u16*)(ws + 0);            // [4096][1024] bf16   (8,388,608 B)
  u16*   wt_cat = (u16*)(ws + 8388608);      // [2176][2048] bf16   (8,912,896 B)
  u16*   wt_out = (u16*)(ws + 17301504);     // [1024][2048] bf16   (4,194,304 B)
  float* bcat   = (float*)(ws + 21495808);   // [2176]
  float* condv  = (float*)(ws + 21504512);   // [4][2048]
  float* dtsum  = (float*)(ws + 21537280);   // [16384]
  float* xpsum  = (float*)(ws + 21602816);   // [16384]
  float* yvec   = (float*)(ws + 21668352);   // [16384]
  float* cA     = (float*)(ws + 21733888);   // [128][64]
  float* cB     = (float*)(ws + 21766656);
  float* hin    = (float*)(ws + 21799424);
  // xn region (32 MiB): live only LN -> GEMM1; afterwards re-used for the
  // f32 scan matrices (Bmat/Cmat/Adisc, 12.6 MB) so peak ws = 244.8 MiB.
  u16*   xn     = (u16*)(ws + 21832192);     // [16384][1024] bf16
  float* Bmat   = (float*)(ws + 21832192);   // [16384][64] f32 (aliases dead xn)
  float* Cmat   = (float*)(ws + 21832192 + 4194304);
  float* Adisc  = (float*)(ws + 21832192 + 8388608);
  u16*   xproj  = (u16*)(ws + 55386624);     // [16384][2048] bf16 (reused as yin)
  u16*   gate   = (u16*)(ws + 122495488);    // [16384][2048] bf16
  u16*   xp     = (u16*)(ws + 189604352);    // [16384][2048] bf16  (ends 256,713,216)

  hipMemsetAsync(dtsum, 0, RTOT * 4, stream);

  wconvT_kernel<<<dim3(NQK/32, HID/32), 256, 0, stream>>>(W_in, wt_in, HID, NQK);
  wconvT_kernel<<<dim3(INTER/32, INTER/32), 256, 0, stream>>>(W_dt, wt_cat, INTER, INTER);
  wconvT_kernel<<<dim3(STATE/32, INTER/32), 256, 0, stream>>>(W_B, wt_cat + (size_t)2048*2048, INTER, STATE);
  wconvT_kernel<<<dim3(STATE/32, INTER/32), 256, 0, stream>>>(W_C, wt_cat + (size_t)2112*2048, INTER, STATE);
  wconvT_kernel<<<dim3(HID/32, INTER/32), 256, 0, stream>>>(W_out, wt_out, INTER, HID);
  bcat_kernel<<<dim3(9), 256, 0, stream>>>(b_dt, dt_bias, b_B, b_C, bcat);
  cond_kernel<<<dim3(INTER/256, BSZ), 256, 0, stream>>>(condition, W_cond, b_cond, condv);
  ln_kernel<<<dim3(RTOT), 256, 0, stream>>>(x, ln_g, ln_b, xn);

  gemm_bt<0><<<dim3(NQK/128, RTOT/128), 256, 0, stream>>>(
      xn, wt_in, HID, b_in, xproj, gate, nullptr, nullptr, nullptr, nullptr, nullptr);

  conv_kernel<<<dim3(RTOT), 256, 0, stream>>>(xproj, conv_w, conv_b, condv, xp, xpsum);

  gemm_bt<1><<<dim3(NCAT/128, RTOT/128), 256, 0, stream>>>(
      xp, wt_cat, INTER, bcat, nullptr, nullptr, dtsum, Bmat, Cmat, nullptr, nullptr);

  scanprep_kernel<<<dim3(RTOT*STATE/256), 256, 0, stream>>>(A_log, dtsum, xpsum, Bmat, Adisc, Bmat);
  scanA_kernel<<<dim3(BSZ*NCH), 64, 0, stream>>>(Adisc, Bmat, cA, cB);
  scanB_kernel<<<dim3(1), 256, 0, stream>>>(cA, cB, hin);
  scanC_kernel<<<dim3(BSZ*NCH), 64, 0, stream>>>(Adisc, Bmat, Cmat, hin, yvec);

  yin_kernel<<<dim3(RTOT*INTER/8/256), 256, 0, stream>>>(xp, gate, yvec, Dp, xproj);

  gemm_bt<2><<<dim3(HID/128, RTOT/128), 256, 0, stream>>>(
      xproj, wt_out, INTER, b_out, nullptr, nullptr, nullptr, nullptr, nullptr, x, (float*)d_out);
}

// Round 5
// 965.020 us; speedup vs baseline: 1.0016x; 1.0016x over previous
//
#include <hip/hip_runtime.h>
#include <stdint.h>

#define HID   1024
#define INTER 2048
#define NQK   4096
#define STATE 64
#define BSZ   4
#define LEN   4096
#define RTOT  (BSZ*LEN)
#define NCAT  2176
#define LC    128
#define NCH   (LEN/LC)

typedef unsigned short u16;
typedef u16   u16x4 __attribute__((ext_vector_type(4)));
typedef u16   u16x8 __attribute__((ext_vector_type(8)));
typedef float f32x4 __attribute__((ext_vector_type(4)));

__device__ __forceinline__ u16 f2bf(float f) {
  uint32_t u = __float_as_uint(f);
  u += 0x7fffu + ((u >> 16) & 1u);
  return (u16)(u >> 16);
}
__device__ __forceinline__ float bf2f(u16 h) {
  return __uint_as_float(((uint32_t)h) << 16);
}

typedef __attribute__((address_space(1))) void gvoid;
typedef __attribute__((address_space(3))) void lvoid;
typedef __attribute__((address_space(3))) u16 lds_u16;
__device__ __forceinline__ void gload16(const void* g, void* l) {
  __builtin_amdgcn_global_load_lds((gvoid*)(uintptr_t)g, (lvoid*)l, 16, 0, 0);
}
__device__ __forceinline__ uint32_t lds_off(const u16* p) {
  return (uint32_t)(uintptr_t)(lds_u16*)p;   // generic -> LDS byte offset
}
__device__ __forceinline__ void mfma16(f32x4 a, f32x4 b, f32x4& c) {
  asm volatile("v_mfma_f32_16x16x32_bf16 %0, %1, %2, %0" : "+v"(c) : "v"(a), "v"(b));
}
__device__ __forceinline__ f32x4 dsread128(uint32_t off) {
  f32x4 r;
  asm volatile("ds_read_b128 %0, %1" : "=v"(r) : "v"(off));
  return r;
}

// ---------------- weight transpose+convert: src [K][N] f32 -> dst [N][K] bf16
__global__ __launch_bounds__(256) void wconvT_kernel(const float* __restrict__ src,
                                                     u16* __restrict__ dst, int K, int N) {
  __shared__ float t[32][33];
  int tx = threadIdx.x & 31, ty = threadIdx.x >> 5;
  int n0 = blockIdx.x * 32, k0 = blockIdx.y * 32;
#pragma unroll
  for (int i = 0; i < 4; ++i)
    t[ty + 8*i][tx] = src[(size_t)(k0 + ty + 8*i) * N + n0 + tx];
  __syncthreads();
#pragma unroll
  for (int i = 0; i < 4; ++i)
    dst[(size_t)(n0 + ty + 8*i) * K + k0 + tx] = f2bf(t[tx][ty + 8*i]);
}

__global__ void bcat_kernel(const float* b_dt, const float* dt_bias, const float* b_B,
                            const float* b_C, float* bcat) {
  int i = blockIdx.x * 256 + threadIdx.x;
  if (i >= NCAT) return;
  float v;
  if (i < INTER) v = b_dt[i] + dt_bias[i];
  else if (i < INTER + STATE) v = b_B[i - INTER];
  else v = b_C[i - INTER - STATE];
  bcat[i] = v;
}

__global__ __launch_bounds__(256) void cond_kernel(const float* __restrict__ condition,
    const float* __restrict__ W, const float* __restrict__ bias, float* __restrict__ out) {
  int b = blockIdx.y;
  int j = blockIdx.x * 256 + threadIdx.x;
  float acc = bias[j];
  const float* crow = condition + b * HID;
  for (int k = 0; k < HID; ++k)
    acc = fmaf(crow[k], W[(size_t)k * INTER + j], acc);
  out[b * INTER + j] = acc;
}

__global__ __launch_bounds__(256) void ln_kernel(const float* __restrict__ x,
    const float* __restrict__ g, const float* __restrict__ bb, u16* __restrict__ xn) {
  int r = blockIdx.x;
  int tid = threadIdx.x;
  const float4 v = ((const float4*)(x + (size_t)r * HID))[tid];
  float s = v.x + v.y + v.z + v.w;
  float sq = v.x*v.x + v.y*v.y + v.z*v.z + v.w*v.w;
  for (int o = 32; o; o >>= 1) { s += __shfl_xor(s, o); sq += __shfl_xor(sq, o); }
  __shared__ float ps[4], pq[4];
  int wid = tid >> 6, lane = tid & 63;
  if (lane == 0) { ps[wid] = s; pq[wid] = sq; }
  __syncthreads();
  s = ps[0] + ps[1] + ps[2] + ps[3];
  sq = pq[0] + pq[1] + pq[2] + pq[3];
  float mu = s * (1.f / HID);
  float var = sq * (1.f / HID) - mu * mu;
  float rstd = rsqrtf(var + 1e-5f);
  int c = tid * 4;
  u16x4 ov;
  ov.x = f2bf((v.x - mu) * rstd * g[c+0] + bb[c+0]);
  ov.y = f2bf((v.y - mu) * rstd * g[c+1] + bb[c+1]);
  ov.z = f2bf((v.z - mu) * rstd * g[c+2] + bb[c+2]);
  ov.w = f2bf((v.w - mu) * rstd * g[c+3] + bb[c+3]);
  *(u16x4*)(xn + (size_t)r * HID + c) = ov;
}

// ============ 256x256 8-phase GEMM: C = A[M,K] * Bt[N,K]^T, bf16 in, f32 acc.
// 8 waves (2M x 4N), BK=64 split in two K-half slots [256][32] per matrix,
// double-buffered (4 slots/matrix, 16KB each, 128KB LDS total).
// Swizzle: chunk_phys = chunk ^ (row&3) (inverse-swizzled global src, linear
// LDS dest for global_load_lds; swizzled ds_read addresses).
// EPI 0: +bias, split cols -> out0 / out1 (bf16)
// EPI 1: softplus(v+bias) row-sum -> atomicAdd dtsum (all cols are dt)
// EPI 2: v + bias + resid -> outf (f32)
template<int EPI>
__global__ __launch_bounds__(512, 2) void gemm256(
    const u16* __restrict__ A, const u16* __restrict__ Bt, int K,
    const float* __restrict__ bias,
    u16* __restrict__ out0, u16* __restrict__ out1,
    float* __restrict__ dtsum,
    const float* __restrict__ resid, float* __restrict__ outf)
{
  __shared__ u16 sA[4 * 8192];
  __shared__ u16 sB[4 * 8192];
  const int tid = threadIdx.x;
  const int lane = tid & 63, wid = tid >> 6;
  const int wm = wid >> 2, wn = wid & 3;
  const int lr = lane & 15, lk = lane >> 4;

  // XCD-aware bijective block swizzle (all grids here are %8 == 0)
  const int nbx = gridDim.x;
  const int nwg = nbx * gridDim.y;
  const int flat = blockIdx.x + nbx * blockIdx.y;
  const int cpx = nwg >> 3;
  const int swz = (flat & 7) * cpx + (flat >> 3);
  const int bx = swz % nbx, by = swz / nbx;
  const int col0 = bx * 256, row0 = by * 256;
  const int NT = K >> 6;

  f32x4 acc[8][4];
#pragma unroll
  for (int i = 0; i < 8; ++i)
#pragma unroll
    for (int j = 0; j < 4; ++j) acc[i][j] = (f32x4){0.f, 0.f, 0.f, 0.f};

  // ---- staging: one slot (16KB, [256 rows][32 K-cols]) = 2 gload_lds calls
  auto stA = [&](int kt, int kh, int bf) {
#pragma unroll
    for (int c = 0; c < 2; ++c) {
      int rl = c * 128 + (tid >> 2);
      int cl = (tid & 3) ^ (rl & 3);
      const u16* src = A + (size_t)(row0 + rl) * K + kt * 64 + kh * 32 + cl * 8;
      gload16(src, &sA[(bf * 2 + kh) * 8192 + c * 4096 + wid * 512]);
    }
  };
  auto stB = [&](int kt, int kh, int bf) {
#pragma unroll
    for (int c = 0; c < 2; ++c) {
      int rl = c * 128 + (tid >> 2);
      int cl = (tid & 3) ^ (rl & 3);
      const u16* src = Bt + (size_t)(col0 + rl) * K + kt * 64 + kh * 32 + cl * 8;
      gload16(src, &sB[(bf * 2 + kh) * 8192 + c * 4096 + wid * 512]);
    }
  };

  const uint32_t offA = lds_off(sA), offB = lds_off(sB);
  // per-thread constant pieces of the frag read address (bytes)
  const uint32_t chunkoff = (uint32_t)((lk ^ (lr & 3)) * 16);
  const uint32_t rowA = (uint32_t)((wm * 128 + lr) * 64) + chunkoff;
  const uint32_t rowB = (uint32_t)((wn * 64 + lr) * 64) + chunkoff;

  // ---- prologue: tile0 kh0, tile0 kh1, tile1 kh0 (6 stages = 12 loads)
  stA(0, 0, 0); stB(0, 0, 0);
  stA(0, 1, 0); stB(0, 1, 0);
  stA(1, 0, 1); stB(1, 0, 1);
  asm volatile("s_waitcnt vmcnt(8)" ::: "memory");   // tile0 kh0 landed
  __builtin_amdgcn_s_barrier();
  __builtin_amdgcn_sched_barrier(0);

#define PHASE(J)                                                               \
  {                                                                            \
    const int kk = (J) >> 1, g = (J) & 1;                                      \
    const uint32_t as = offA + (uint32_t)((p * 2 + kk) * 16384);               \
    const uint32_t bs = offB + (uint32_t)((p * 2 + kk) * 16384);               \
    f32x4 aF[4], bF[4];                                                        \
    aF[0] = dsread128(as + rowA + (g * 4 + 0) * 1024);                         \
    aF[1] = dsread128(as + rowA + (g * 4 + 1) * 1024);                         \
    aF[2] = dsread128(as + rowA + (g * 4 + 2) * 1024);                         \
    aF[3] = dsread128(as + rowA + (g * 4 + 3) * 1024);                         \
    bF[0] = dsread128(bs + rowB + 0 * 1024);                                   \
    bF[1] = dsread128(bs + rowB + 1 * 1024);                                   \
    bF[2] = dsread128(bs + rowB + 2 * 1024);                                   \
    bF[3] = dsread128(bs + rowB + 3 * 1024);                                   \
    if ((J) == 0 && t + 1 < NT) stA(t + 1, 1, p ^ 1);                          \
    if ((J) == 1 && t + 1 < NT) stB(t + 1, 1, p ^ 1);                          \
    if ((J) == 2 && t + 2 < NT) stA(t + 2, 0, p);                              \
    if ((J) == 3 && t + 2 < NT) stB(t + 2, 0, p);                              \
    __builtin_amdgcn_s_barrier();                                              \
    asm volatile("s_waitcnt lgkmcnt(0)" ::: "memory");                         \
    __builtin_amdgcn_sched_barrier(0);                                         \
    __builtin_amdgcn_s_setprio(1);                                             \
    _Pragma("unroll")                                                          \
    for (int f = 0; f < 4; ++f)                                                \
      _Pragma("unroll")                                                        \
      for (int n = 0; n < 4; ++n)                                              \
        mfma16(aF[f], bF[n], acc[g * 4 + f][n]);                               \
    __builtin_amdgcn_s_setprio(0);                                             \
    if ((J) == 1 || (J) == 3)                                                  \
      asm volatile("s_waitcnt vmcnt(6)" ::: "memory");                         \
    __builtin_amdgcn_s_barrier();                                              \
    __builtin_amdgcn_sched_barrier(0);                                         \
  }

  for (int t = 0; t < NT; ++t) {
    const int p = t & 1;
    PHASE(0)
    PHASE(1)
    PHASE(2)
    PHASE(3)
  }
#undef PHASE

  // MFMA -> VALU hazard guard (inline-asm MFMA gets no compiler hazard nops)
  asm volatile("s_nop 7\n\ts_nop 7");

  // ---- epilogue
  const int rb = row0 + wm * 128;
  const int cb = col0 + wn * 64;

  if constexpr (EPI == 0) {
#pragma unroll
    for (int fm = 0; fm < 8; ++fm)
#pragma unroll
      for (int fn = 0; fn < 4; ++fn)
#pragma unroll
        for (int rr = 0; rr < 4; ++rr) {
          int rowg = rb + fm * 16 + lk * 4 + rr;
          int colg = cb + fn * 16 + lr;
          float v = acc[fm][fn][rr] + bias[colg];
          if (col0 < INTER) out0[(size_t)rowg * INTER + colg] = f2bf(v);
          else              out1[(size_t)rowg * INTER + colg - INTER] = f2bf(v);
        }
  } else if constexpr (EPI == 1) {
#pragma unroll
    for (int fm = 0; fm < 8; ++fm)
#pragma unroll
      for (int rr = 0; rr < 4; ++rr) {
        float s = 0.f;
#pragma unroll
        for (int fn = 0; fn < 4; ++fn) {
          int colg = cb + fn * 16 + lr;
          float v = acc[fm][fn][rr] + bias[colg];
          s += (v > 20.f) ? v : log1pf(expf(v));
        }
#pragma unroll
        for (int o = 1; o < 16; o <<= 1) s += __shfl_xor(s, o);
        if (lr == 0) atomicAdd(&dtsum[rb + fm * 16 + lk * 4 + rr], s);
      }
  } else {
#pragma unroll
    for (int fm = 0; fm < 8; ++fm)
#pragma unroll
      for (int fn = 0; fn < 4; ++fn)
#pragma unroll
        for (int rr = 0; rr < 4; ++rr) {
          int rowg = rb + fm * 16 + lk * 4 + rr;
          int colg = cb + fn * 16 + lr;
          float v = acc[fm][fn][rr] + bias[colg];
          outf[(size_t)rowg * HID + colg] = v + resid[(size_t)rowg * HID + colg];
        }
  }
}

// ---------------- old 128x128 GEMM, kept for the B/C columns (N=128, EPI 3)
template<int EPI>
__global__ __launch_bounds__(256) void gemm_bt(
    const u16* __restrict__ A, const u16* __restrict__ Bt, int K,
    const float* __restrict__ bias,
    float* __restrict__ Bmat, float* __restrict__ Cmat)
{
  __shared__ u16 lA[128 * 32];
  __shared__ u16 lB[128 * 32];
  const int tid = threadIdx.x;
  const int lane = tid & 63;
  const int wid = tid >> 6;
  const int wm = wid >> 1, wn = wid & 1;
  const int lr = lane & 15, lk = lane >> 4;
  const int col0 = blockIdx.x * 128;
  const int row0 = blockIdx.y * 128;
  const int wbase = tid & 192;

  f32x4 acc[4][4];
#pragma unroll
  for (int i = 0; i < 4; ++i)
#pragma unroll
    for (int j = 0; j < 4; ++j) acc[i][j] = (f32x4){0.f, 0.f, 0.f, 0.f};

  const size_t arow = (size_t)row0 * K;
  const size_t brow = (size_t)col0 * K;

  for (int kt = 0; kt < K; kt += 32) {
    __syncthreads();
#pragma unroll
    for (int j = 0; j < 2; ++j) {
      int cbase = j * 256 + wbase;
      int chunk = cbase + lane;
      gload16(A + arow + (size_t)(chunk >> 2) * K + kt + (chunk & 3) * 8, &lA[cbase * 8]);
    }
#pragma unroll
    for (int j = 0; j < 2; ++j) {
      int cbase = j * 256 + wbase;
      int chunk = cbase + lane;
      gload16(Bt + brow + (size_t)(chunk >> 2) * K + kt + (chunk & 3) * 8, &lB[cbase * 8]);
    }
    __syncthreads();
    f32x4 aF[4], bF[4];
#pragma unroll
    for (int f = 0; f < 4; ++f)
      aF[f] = *(const f32x4*)&lA[(wm * 64 + f * 16 + lr) * 32 + lk * 8];
#pragma unroll
    for (int f = 0; f < 4; ++f)
      bF[f] = *(const f32x4*)&lB[(wn * 64 + f * 16 + lr) * 32 + lk * 8];
#pragma unroll
    for (int fm = 0; fm < 4; ++fm)
#pragma unroll
      for (int fn = 0; fn < 4; ++fn)
        mfma16(aF[fm], bF[fn], acc[fm][fn]);
  }
  asm volatile("s_nop 7\n\ts_nop 7");

  const int rb = row0 + wm * 64;
  if constexpr (EPI == 3) {
    // B/C columns; bias pre-offset by caller; col0 == 0, N-tile = 128
#pragma unroll
    for (int fm = 0; fm < 4; ++fm)
#pragma unroll
      for (int fn = 0; fn < 4; ++fn)
#pragma unroll
        for (int rr = 0; rr < 4; ++rr) {
          int rowg = rb + fm * 16 + lk * 4 + rr;
          int colL = wn * 64 + fn * 16 + lr;
          float v = acc[fm][fn][rr] + bias[colL];
          if (colL < STATE) Bmat[(size_t)rowg * STATE + colL] = v;
          else              Cmat[(size_t)rowg * STATE + colL - STATE] = v;
        }
  }
}

// depthwise conv3 (pad 1) + conv_b + silu + cond add; also row-sum of xp
__global__ __launch_bounds__(256) void conv_kernel(
    const u16* __restrict__ xproj, const float* __restrict__ cw, const float* __restrict__ cbias,
    const float* __restrict__ condv, u16* __restrict__ xp, float* __restrict__ xpsum)
{
  int r = blockIdx.x;
  int b = r >> 12, l = r & (LEN - 1);
  int c0 = threadIdx.x * 8;
  const u16* base = xproj + (size_t)r * INTER + c0;
  u16x8 x0 = *(const u16x8*)base;
  u16x8 xm = (u16x8){0,0,0,0,0,0,0,0};
  u16x8 xpv = (u16x8){0,0,0,0,0,0,0,0};
  if (l > 0)       xm  = *(const u16x8*)(base - INTER);
  if (l < LEN - 1) xpv = *(const u16x8*)(base + INTER);
  float sum = 0.f;
  u16x8 ov;
#pragma unroll
  for (int j = 0; j < 8; ++j) {
    int c = c0 + j;
    float v = cw[c*3+0] * bf2f(xm[j]) + cw[c*3+1] * bf2f(x0[j]) + cw[c*3+2] * bf2f(xpv[j]) + cbias[c];
    float sg = v / (1.f + expf(-v));
    float o = sg + condv[b * INTER + c];
    sum += o;
    ov[j] = f2bf(o);
  }
  *(u16x8*)(xp + (size_t)r * INTER + c0) = ov;
  for (int o = 32; o; o >>= 1) sum += __shfl_xor(sum, o);
  __shared__ float ps[4];
  if ((threadIdx.x & 63) == 0) ps[threadIdx.x >> 6] = sum;
  __syncthreads();
  if (threadIdx.x == 0) xpsum[r] = ps[0] + ps[1] + ps[2] + ps[3];
}

__global__ __launch_bounds__(256) void scanprep_kernel(const float* __restrict__ A_log,
    const float* __restrict__ dtsum, const float* __restrict__ xpsum,
    const float* BmatIn, float* Adisc, float* Bx)
{
  int e = blockIdx.x * 256 + threadIdx.x;
  int r = e >> 6, s = e & 63;
  float dtm = dtsum[r] * (1.f / INTER);
  float xpm = xpsum[r] * (1.f / INTER);
  Adisc[e] = expf(-expf(A_log[s]) * dtm);
  Bx[e] = BmatIn[e] * dtm * xpm;
}

__global__ __launch_bounds__(64) void scanA_kernel(const float* __restrict__ Adisc,
    const float* __restrict__ Bx, float* __restrict__ cA, float* __restrict__ cB)
{
  int g = blockIdx.x; int b = g / NCH, ch = g % NCH;
  int s = threadIdx.x;
  float ap = 1.f, bacc = 0.f;
  size_t base = ((size_t)(b * LEN + ch * LC) << 6) + s;
  for (int i = 0; i < LC; ++i) {
    float a = Adisc[base], bb = Bx[base];
    bacc = fmaf(a, bacc, bb);
    ap *= a;
    base += 64;
  }
  cA[(size_t)g * 64 + s] = ap;
  cB[(size_t)g * 64 + s] = bacc;
}

__global__ __launch_bounds__(256) void scanB_kernel(const float* __restrict__ cA,
    const float* __restrict__ cB, float* __restrict__ hin)
{
  int t = threadIdx.x; int b = t >> 6, s = t & 63;
  float h = 0.f;
  for (int ch = 0; ch < NCH; ++ch) {
    size_t i = (size_t)(b * NCH + ch) * 64 + s;
    hin[i] = h;
    h = fmaf(cA[i], h, cB[i]);
  }
}

__global__ __launch_bounds__(64) void scanC_kernel(const float* __restrict__ Adisc,
    const float* __restrict__ Bx, const float* __restrict__ Cmat,
    const float* __restrict__ hin, float* __restrict__ yvec)
{
  int g = blockIdx.x; int b = g / NCH, ch = g % NCH;
  int s = threadIdx.x;
  float h = hin[(size_t)g * 64 + s];
  int l0 = ch * LC;
  size_t base = ((size_t)(b * LEN + l0) << 6) + s;
  for (int i = 0; i < LC; ++i) {
    h = fmaf(Adisc[base], h, Bx[base]);
    float p = Cmat[base] * h;
    for (int o = 32; o; o >>= 1) p += __shfl_xor(p, o);
    if (s == 0) yvec[b * LEN + l0 + i] = p;
    base += 64;
  }
}

__global__ __launch_bounds__(256) void yin_kernel(const u16* __restrict__ xp,
    const u16* __restrict__ gate, const float* __restrict__ yvec,
    const float* __restrict__ Dp, u16* __restrict__ yin)
{
  int i = blockIdx.x * 256 + threadIdx.x;
  int r = i >> 8;
  int c0 = (i & 255) * 8;
  size_t off = (size_t)r * INTER + c0;
  u16x8 xv = *(const u16x8*)(xp + off);
  u16x8 gv = *(const u16x8*)(gate + off);
  float yv = yvec[r];
  u16x8 ov;
#pragma unroll
  for (int j = 0; j < 8; ++j) {
    float g = bf2f(gv[j]);
    float sg = g / (1.f + expf(-g));
    float val = (yv + bf2f(xv[j]) * Dp[c0 + j]) * sg;
    ov[j] = f2bf(val);
  }
  *(u16x8*)(yin + off) = ov;
}

extern "C" void kernel_launch(void* const* d_in, const int* in_sizes, int n_in,
                              void* d_out, int out_size, void* d_ws, size_t ws_size,
                              hipStream_t stream) {
  (void)in_sizes; (void)n_in; (void)out_size; (void)ws_size;
  const float* x         = (const float*)d_in[0];
  const float* condition = (const float*)d_in[1];
  const float* ln_g      = (const float*)d_in[2];
  const float* ln_b      = (const float*)d_in[3];
  const float* W_in      = (const float*)d_in[4];
  const float* b_in      = (const float*)d_in[5];
  const float* conv_w    = (const float*)d_in[6];
  const float* conv_b    = (const float*)d_in[7];
  const float* W_dt      = (const float*)d_in[8];
  const float* b_dt      = (const float*)d_in[9];
  const float* dt_bias   = (const float*)d_in[10];
  const float* A_log     = (const float*)d_in[11];
  const float* Dp        = (const float*)d_in[12];
  const float* W_B       = (const float*)d_in[13];
  const float* b_B       = (const float*)d_in[14];
  const float* W_C       = (const float*)d_in[15];
  const float* b_C       = (const float*)d_in[16];
  const float* W_cond    = (const float*)d_in[17];
  const float* b_cond    = (const float*)d_in[18];
  const float* W_out     = (const float*)d_in[19];
  const float* b_out     = (const float*)d_in[20];

  char* ws = (char*)d_ws;
  u16*   wt_in  = (u16*)(ws + 0);            // [4096][1024] bf16
  u16*   wt_cat = (u16*)(ws + 8388608);      // [2176][2048] bf16
  u16*   wt_out = (u16*)(ws + 17301504);     // [1024][2048] bf16
  float* bcat   = (float*)(ws + 21495808);   // [2176]
  float* condv  = (float*)(ws + 21504512);   // [4][2048]
  float* dtsum  = (float*)(ws + 21537280);   // [16384]
  float* xpsum  = (float*)(ws + 21602816);   // [16384]
  float* yvec   = (float*)(ws + 21668352);   // [16384]
  float* cA     = (float*)(ws + 21733888);   // [128][64]
  float* cB     = (float*)(ws + 21766656);
  float* hin    = (float*)(ws + 21799424);
  u16*   xn     = (u16*)(ws + 21832192);     // [16384][1024] bf16 (dead after GEMM1)
  float* Bmat   = (float*)(ws + 21832192);   // aliases dead xn
  float* Cmat   = (float*)(ws + 21832192 + 4194304);
  float* Adisc  = (float*)(ws + 21832192 + 8388608);
  u16*   xproj  = (u16*)(ws + 55386624);     // [16384][2048] bf16 (reused as yin)
  u16*   gate   = (u16*)(ws + 122495488);    // [16384][2048] bf16
  u16*   xp     = (u16*)(ws + 189604352);    // [16384][2048] bf16

  hipMemsetAsync(dtsum, 0, RTOT * 4, stream);

  wconvT_kernel<<<dim3(NQK/32, HID/32), 256, 0, stream>>>(W_in, wt_in, HID, NQK);
  wconvT_kernel<<<dim3(INTER/32, INTER/32), 256, 0, stream>>>(W_dt, wt_cat, INTER, INTER);
  wconvT_kernel<<<dim3(STATE/32, INTER/32), 256, 0, stream>>>(W_B, wt_cat + (size_t)2048*2048, INTER, STATE);
  wconvT_kernel<<<dim3(STATE/32, INTER/32), 256, 0, stream>>>(W_C, wt_cat + (size_t)2112*2048, INTER, STATE);
  wconvT_kernel<<<dim3(HID/32, INTER/32), 256, 0, stream>>>(W_out, wt_out, INTER, HID);
  bcat_kernel<<<dim3(9), 256, 0, stream>>>(b_dt, dt_bias, b_B, b_C, bcat);
  cond_kernel<<<dim3(INTER/256, BSZ), 256, 0, stream>>>(condition, W_cond, b_cond, condv);
  ln_kernel<<<dim3(RTOT), 256, 0, stream>>>(x, ln_g, ln_b, xn);

  gemm256<0><<<dim3(NQK/256, RTOT/256), 512, 0, stream>>>(
      xn, wt_in, HID, b_in, xproj, gate, nullptr, nullptr, nullptr);

  conv_kernel<<<dim3(RTOT), 256, 0, stream>>>(xproj, conv_w, conv_b, condv, xp, xpsum);

  // dt part (cols 0..2047) on the 8-phase kernel
  gemm256<1><<<dim3(INTER/256, RTOT/256), 512, 0, stream>>>(
      xp, wt_cat, INTER, bcat, nullptr, nullptr, dtsum, nullptr, nullptr);
  // B/C part (128 cols) on the old 128^2 kernel
  gemm_bt<3><<<dim3(1, RTOT/128), 256, 0, stream>>>(
      xp, wt_cat + (size_t)2048*2048, INTER, bcat + INTER, Bmat, Cmat);

  scanprep_kernel<<<dim3(RTOT*STATE/256), 256, 0, stream>>>(A_log, dtsum, xpsum, Bmat, Adisc, Bmat);
  scanA_kernel<<<dim3(BSZ*NCH), 64, 0, stream>>>(Adisc, Bmat, cA, cB);
  scanB_kernel<<<dim3(1), 256, 0, stream>>>(cA, cB, hin);
  scanC_kernel<<<dim3(BSZ*NCH), 64, 0, stream>>>(Adisc, Bmat, Cmat, hin, yvec);

  yin_kernel<<<dim3(RTOT*INTER/8/256), 256, 0, stream>>>(xp, gate, yvec, Dp, xproj);

  gemm256<2><<<dim3(HID/256, RTOT/256), 512, 0, stream>>>(
      xproj, wt_out, INTER, b_out, nullptr, nullptr, nullptr, x, (float*)d_out);
}

// Round 6
// 923.961 us; speedup vs baseline: 1.0461x; 1.0444x over previous
//
#include <hip/hip_runtime.h>
#include <stdint.h>

#define HID   1024
#define INTER 2048
#define NQK   4096
#define STATE 64
#define BSZ   4
#define LEN   4096
#define RTOT  (BSZ*LEN)
#define NCAT  2176
#define LC    128
#define NCH   (LEN/LC)

typedef unsigned short u16;
typedef u16   u16x4 __attribute__((ext_vector_type(4)));
typedef u16   u16x8 __attribute__((ext_vector_type(8)));
typedef float f32x4 __attribute__((ext_vector_type(4)));

__device__ __forceinline__ u16 f2bf(float f) {
  uint32_t u = __float_as_uint(f);
  u += 0x7fffu + ((u >> 16) & 1u);
  return (u16)(u >> 16);
}
__device__ __forceinline__ float bf2f(u16 h) {
  return __uint_as_float(((uint32_t)h) << 16);
}

typedef __attribute__((address_space(1))) void gvoid;
typedef __attribute__((address_space(3))) void lvoid;
typedef __attribute__((address_space(3))) u16 lds_u16;
__device__ __forceinline__ void gload16(const void* g, void* l) {
  __builtin_amdgcn_global_load_lds((gvoid*)(uintptr_t)g, (lvoid*)l, 16, 0, 0);
}
__device__ __forceinline__ uint32_t lds_off(const u16* p) {
  return (uint32_t)(uintptr_t)(lds_u16*)p;   // generic -> LDS byte offset
}
__device__ __forceinline__ void mfma16(f32x4 a, f32x4 b, f32x4& c) {
  asm volatile("v_mfma_f32_16x16x32_bf16 %0, %1, %2, %0" : "+v"(c) : "v"(a), "v"(b));
}
__device__ __forceinline__ f32x4 dsread128(uint32_t off) {
  f32x4 r;
  asm volatile("ds_read_b128 %0, %1" : "=v"(r) : "v"(off));
  return r;
}

// ---------------- weight transpose+convert: src [K][N] f32 -> dst [N][K] bf16
__global__ __launch_bounds__(256) void wconvT_kernel(const float* __restrict__ src,
                                                     u16* __restrict__ dst, int K, int N) {
  __shared__ float t[32][33];
  int tx = threadIdx.x & 31, ty = threadIdx.x >> 5;
  int n0 = blockIdx.x * 32, k0 = blockIdx.y * 32;
#pragma unroll
  for (int i = 0; i < 4; ++i)
    t[ty + 8*i][tx] = src[(size_t)(k0 + ty + 8*i) * N + n0 + tx];
  __syncthreads();
#pragma unroll
  for (int i = 0; i < 4; ++i)
    dst[(size_t)(n0 + ty + 8*i) * K + k0 + tx] = f2bf(t[tx][ty + 8*i]);
}

__global__ void bcat_kernel(const float* b_dt, const float* dt_bias, const float* b_B,
                            const float* b_C, float* bcat) {
  int i = blockIdx.x * 256 + threadIdx.x;
  if (i >= NCAT) return;
  float v;
  if (i < INTER) v = b_dt[i] + dt_bias[i];
  else if (i < INTER + STATE) v = b_B[i - INTER];
  else v = b_C[i - INTER - STATE];
  bcat[i] = v;
}

__global__ __launch_bounds__(256) void cond_kernel(const float* __restrict__ condition,
    const float* __restrict__ W, const float* __restrict__ bias, float* __restrict__ out) {
  int b = blockIdx.y;
  int j = blockIdx.x * 256 + threadIdx.x;
  float acc = bias[j];
  const float* crow = condition + b * HID;
  for (int k = 0; k < HID; ++k)
    acc = fmaf(crow[k], W[(size_t)k * INTER + j], acc);
  out[b * INTER + j] = acc;
}

__global__ __launch_bounds__(256) void ln_kernel(const float* __restrict__ x,
    const float* __restrict__ g, const float* __restrict__ bb, u16* __restrict__ xn) {
  int r = blockIdx.x;
  int tid = threadIdx.x;
  const float4 v = ((const float4*)(x + (size_t)r * HID))[tid];
  float s = v.x + v.y + v.z + v.w;
  float sq = v.x*v.x + v.y*v.y + v.z*v.z + v.w*v.w;
  for (int o = 32; o; o >>= 1) { s += __shfl_xor(s, o); sq += __shfl_xor(sq, o); }
  __shared__ float ps[4], pq[4];
  int wid = tid >> 6, lane = tid & 63;
  if (lane == 0) { ps[wid] = s; pq[wid] = sq; }
  __syncthreads();
  s = ps[0] + ps[1] + ps[2] + ps[3];
  sq = pq[0] + pq[1] + pq[2] + pq[3];
  float mu = s * (1.f / HID);
  float var = sq * (1.f / HID) - mu * mu;
  float rstd = rsqrtf(var + 1e-5f);
  int c = tid * 4;
  u16x4 ov;
  ov.x = f2bf((v.x - mu) * rstd * g[c+0] + bb[c+0]);
  ov.y = f2bf((v.y - mu) * rstd * g[c+1] + bb[c+1]);
  ov.z = f2bf((v.z - mu) * rstd * g[c+2] + bb[c+2]);
  ov.w = f2bf((v.w - mu) * rstd * g[c+3] + bb[c+3]);
  *(u16x4*)(xn + (size_t)r * HID + c) = ov;
}

// ============ 256x256 8-phase GEMM: C = A[M,K] * Bt[N,K]^T, bf16 in, f32 acc.
// 8 waves (2M x 4N), BK=64 split in two K-half slots [256][32] per matrix,
// double-buffered (4 slots/matrix, 16KB each, 128KB LDS total).
// Swizzle: chunk_phys = chunk ^ ((row>>1)&3): quarter-wave quad index
// 4*(lr&1) + (lk ^ ((lr>>1)&3)) hits all 8 bank-quads exactly twice ->
// 2 lanes/bank = conflict-free (m136). Round-5's (row&3) mask only gave
// 4-way (lr&3 takes {0,2} on even lanes) and left 1.68e7 conflicts.
// EPI 0: +bias, split cols -> out0 / out1 (bf16)
// EPI 1: softplus(v+bias) row-sum -> atomicAdd dtsum (all cols are dt)
// EPI 2: v + bias + resid -> outf (f32)
template<int EPI>
__global__ __launch_bounds__(512, 2) void gemm256(
    const u16* __restrict__ A, const u16* __restrict__ Bt, int K,
    const float* __restrict__ bias,
    u16* __restrict__ out0, u16* __restrict__ out1,
    float* __restrict__ dtsum,
    const float* __restrict__ resid, float* __restrict__ outf)
{
  __shared__ u16 sA[4 * 8192];
  __shared__ u16 sB[4 * 8192];
  const int tid = threadIdx.x;
  const int lane = tid & 63, wid = tid >> 6;
  const int wm = wid >> 2, wn = wid & 3;
  const int lr = lane & 15, lk = lane >> 4;

  // XCD-aware bijective block swizzle (all grids here are %8 == 0)
  const int nbx = gridDim.x;
  const int nwg = nbx * gridDim.y;
  const int flat = blockIdx.x + nbx * blockIdx.y;
  const int cpx = nwg >> 3;
  const int swz = (flat & 7) * cpx + (flat >> 3);
  const int bx = swz % nbx, by = swz / nbx;
  const int col0 = bx * 256, row0 = by * 256;
  const int NT = K >> 6;

  f32x4 acc[8][4];
#pragma unroll
  for (int i = 0; i < 8; ++i)
#pragma unroll
    for (int j = 0; j < 4; ++j) acc[i][j] = (f32x4){0.f, 0.f, 0.f, 0.f};

  // ---- staging: one slot (16KB, [256 rows][32 K-cols]) = 2 gload_lds calls
  auto stA = [&](int kt, int kh, int bf) {
#pragma unroll
    for (int c = 0; c < 2; ++c) {
      int rl = c * 128 + (tid >> 2);
      int cl = (tid & 3) ^ ((rl >> 1) & 3);
      const u16* src = A + (size_t)(row0 + rl) * K + kt * 64 + kh * 32 + cl * 8;
      gload16(src, &sA[(bf * 2 + kh) * 8192 + c * 4096 + wid * 512]);
    }
  };
  auto stB = [&](int kt, int kh, int bf) {
#pragma unroll
    for (int c = 0; c < 2; ++c) {
      int rl = c * 128 + (tid >> 2);
      int cl = (tid & 3) ^ ((rl >> 1) & 3);
      const u16* src = Bt + (size_t)(col0 + rl) * K + kt * 64 + kh * 32 + cl * 8;
      gload16(src, &sB[(bf * 2 + kh) * 8192 + c * 4096 + wid * 512]);
    }
  };

  const uint32_t offA = lds_off(sA), offB = lds_off(sB);
  // per-thread constant pieces of the frag read address (bytes);
  // fragment-row offsets (f*16, wm*128, wn*64) are multiples of 16 rows so
  // (row>>1)&3 == (lr>>1)&3 for every fragment.
  const uint32_t chunkoff = (uint32_t)((lk ^ ((lr >> 1) & 3)) * 16);
  const uint32_t rowA = (uint32_t)((wm * 128 + lr) * 64) + chunkoff;
  const uint32_t rowB = (uint32_t)((wn * 64 + lr) * 64) + chunkoff;

  // ---- prologue: tile0 kh0, tile0 kh1, tile1 kh0 (6 stages = 12 loads)
  stA(0, 0, 0); stB(0, 0, 0);
  stA(0, 1, 0); stB(0, 1, 0);
  stA(1, 0, 1); stB(1, 0, 1);
  asm volatile("s_waitcnt vmcnt(8)" ::: "memory");   // tile0 kh0 landed
  __builtin_amdgcn_s_barrier();
  __builtin_amdgcn_sched_barrier(0);

#define PHASE(J)                                                               \
  {                                                                            \
    const int kk = (J) >> 1, g = (J) & 1;                                      \
    const uint32_t as = offA + (uint32_t)((p * 2 + kk) * 16384);               \
    const uint32_t bs = offB + (uint32_t)((p * 2 + kk) * 16384);               \
    f32x4 aF[4], bF[4];                                                        \
    aF[0] = dsread128(as + rowA + (g * 4 + 0) * 1024);                         \
    aF[1] = dsread128(as + rowA + (g * 4 + 1) * 1024);                         \
    aF[2] = dsread128(as + rowA + (g * 4 + 2) * 1024);                         \
    aF[3] = dsread128(as + rowA + (g * 4 + 3) * 1024);                         \
    bF[0] = dsread128(bs + rowB + 0 * 1024);                                   \
    bF[1] = dsread128(bs + rowB + 1 * 1024);                                   \
    bF[2] = dsread128(bs + rowB + 2 * 1024);                                   \
    bF[3] = dsread128(bs + rowB + 3 * 1024);                                   \
    if ((J) == 0 && t + 1 < NT) stA(t + 1, 1, p ^ 1);                          \
    if ((J) == 1 && t + 1 < NT) stB(t + 1, 1, p ^ 1);                          \
    if ((J) == 2 && t + 2 < NT) stA(t + 2, 0, p);                              \
    if ((J) == 3 && t + 2 < NT) stB(t + 2, 0, p);                              \
    __builtin_amdgcn_s_barrier();                                              \
    asm volatile("s_waitcnt lgkmcnt(0)" ::: "memory");                         \
    __builtin_amdgcn_sched_barrier(0);                                         \
    __builtin_amdgcn_s_setprio(1);                                             \
    _Pragma("unroll")                                                          \
    for (int f = 0; f < 4; ++f)                                                \
      _Pragma("unroll")                                                        \
      for (int n = 0; n < 4; ++n)                                              \
        mfma16(aF[f], bF[n], acc[g * 4 + f][n]);                               \
    __builtin_amdgcn_s_setprio(0);                                             \
    if ((J) == 1 || (J) == 3)                                                  \
      asm volatile("s_waitcnt vmcnt(6)" ::: "memory");                         \
    __builtin_amdgcn_s_barrier();                                              \
    __builtin_amdgcn_sched_barrier(0);                                         \
  }

  for (int t = 0; t < NT; ++t) {
    const int p = t & 1;
    PHASE(0)
    PHASE(1)
    PHASE(2)
    PHASE(3)
  }
#undef PHASE

  // MFMA -> VALU hazard guard (inline-asm MFMA gets no compiler hazard nops)
  asm volatile("s_nop 7\n\ts_nop 7");

  // ---- epilogue
  const int rb = row0 + wm * 128;
  const int cb = col0 + wn * 64;

  if constexpr (EPI == 0) {
#pragma unroll
    for (int fm = 0; fm < 8; ++fm)
#pragma unroll
      for (int fn = 0; fn < 4; ++fn)
#pragma unroll
        for (int rr = 0; rr < 4; ++rr) {
          int rowg = rb + fm * 16 + lk * 4 + rr;
          int colg = cb + fn * 16 + lr;
          float v = acc[fm][fn][rr] + bias[colg];
          if (col0 < INTER) out0[(size_t)rowg * INTER + colg] = f2bf(v);
          else              out1[(size_t)rowg * INTER + colg - INTER] = f2bf(v);
        }
  } else if constexpr (EPI == 1) {
#pragma unroll
    for (int fm = 0; fm < 8; ++fm)
#pragma unroll
      for (int rr = 0; rr < 4; ++rr) {
        float s = 0.f;
#pragma unroll
        for (int fn = 0; fn < 4; ++fn) {
          int colg = cb + fn * 16 + lr;
          float v = acc[fm][fn][rr] + bias[colg];
          s += (v > 20.f) ? v : log1pf(expf(v));
        }
#pragma unroll
        for (int o = 1; o < 16; o <<= 1) s += __shfl_xor(s, o);
        if (lr == 0) atomicAdd(&dtsum[rb + fm * 16 + lk * 4 + rr], s);
      }
  } else {
#pragma unroll
    for (int fm = 0; fm < 8; ++fm)
#pragma unroll
      for (int fn = 0; fn < 4; ++fn)
#pragma unroll
        for (int rr = 0; rr < 4; ++rr) {
          int rowg = rb + fm * 16 + lk * 4 + rr;
          int colg = cb + fn * 16 + lr;
          float v = acc[fm][fn][rr] + bias[colg];
          outf[(size_t)rowg * HID + colg] = v + resid[(size_t)rowg * HID + colg];
        }
  }
}

// ---------------- old 128x128 GEMM, kept for the B/C columns (N=128, EPI 3)
// Same (row>>1)&3 chunk swizzle applied (rows are also 64 B here).
template<int EPI>
__global__ __launch_bounds__(256) void gemm_bt(
    const u16* __restrict__ A, const u16* __restrict__ Bt, int K,
    const float* __restrict__ bias,
    float* __restrict__ Bmat, float* __restrict__ Cmat)
{
  __shared__ u16 lA[128 * 32];
  __shared__ u16 lB[128 * 32];
  const int tid = threadIdx.x;
  const int lane = tid & 63;
  const int wid = tid >> 6;
  const int wm = wid >> 1, wn = wid & 1;
  const int lr = lane & 15, lk = lane >> 4;
  const int col0 = blockIdx.x * 128;
  const int row0 = blockIdx.y * 128;
  const int wbase = tid & 192;
  const int ckoff = (lk ^ ((lr >> 1) & 3)) * 8;

  f32x4 acc[4][4];
#pragma unroll
  for (int i = 0; i < 4; ++i)
#pragma unroll
    for (int j = 0; j < 4; ++j) acc[i][j] = (f32x4){0.f, 0.f, 0.f, 0.f};

  const size_t arow = (size_t)row0 * K;
  const size_t brow = (size_t)col0 * K;

  for (int kt = 0; kt < K; kt += 32) {
    __syncthreads();
#pragma unroll
    for (int j = 0; j < 2; ++j) {
      int cbase = j * 256 + wbase;
      int chunk = cbase + lane;
      int cl = (chunk & 3) ^ (((chunk >> 2) >> 1) & 3);
      gload16(A + arow + (size_t)(chunk >> 2) * K + kt + cl * 8, &lA[cbase * 8]);
    }
#pragma unroll
    for (int j = 0; j < 2; ++j) {
      int cbase = j * 256 + wbase;
      int chunk = cbase + lane;
      int cl = (chunk & 3) ^ (((chunk >> 2) >> 1) & 3);
      gload16(Bt + brow + (size_t)(chunk >> 2) * K + kt + cl * 8, &lB[cbase * 8]);
    }
    __syncthreads();
    f32x4 aF[4], bF[4];
#pragma unroll
    for (int f = 0; f < 4; ++f)
      aF[f] = *(const f32x4*)&lA[(wm * 64 + f * 16 + lr) * 32 + ckoff];
#pragma unroll
    for (int f = 0; f < 4; ++f)
      bF[f] = *(const f32x4*)&lB[(wn * 64 + f * 16 + lr) * 32 + ckoff];
#pragma unroll
    for (int fm = 0; fm < 4; ++fm)
#pragma unroll
      for (int fn = 0; fn < 4; ++fn)
        mfma16(aF[fm], bF[fn], acc[fm][fn]);
  }
  asm volatile("s_nop 7\n\ts_nop 7");

  const int rb = row0 + wm * 64;
  if constexpr (EPI == 3) {
    // B/C columns; bias pre-offset by caller; col0 == 0, N-tile = 128
#pragma unroll
    for (int fm = 0; fm < 4; ++fm)
#pragma unroll
      for (int fn = 0; fn < 4; ++fn)
#pragma unroll
        for (int rr = 0; rr < 4; ++rr) {
          int rowg = rb + fm * 16 + lk * 4 + rr;
          int colL = wn * 64 + fn * 16 + lr;
          float v = acc[fm][fn][rr] + bias[colL];
          if (colL < STATE) Bmat[(size_t)rowg * STATE + colL] = v;
          else              Cmat[(size_t)rowg * STATE + colL - STATE] = v;
        }
  }
}

// depthwise conv3 (pad 1) + conv_b + silu + cond add; also row-sum of xp
__global__ __launch_bounds__(256) void conv_kernel(
    const u16* __restrict__ xproj, const float* __restrict__ cw, const float* __restrict__ cbias,
    const float* __restrict__ condv, u16* __restrict__ xp, float* __restrict__ xpsum)
{
  int r = blockIdx.x;
  int b = r >> 12, l = r & (LEN - 1);
  int c0 = threadIdx.x * 8;
  const u16* base = xproj + (size_t)r * INTER + c0;
  u16x8 x0 = *(const u16x8*)base;
  u16x8 xm = (u16x8){0,0,0,0,0,0,0,0};
  u16x8 xpv = (u16x8){0,0,0,0,0,0,0,0};
  if (l > 0)       xm  = *(const u16x8*)(base - INTER);
  if (l < LEN - 1) xpv = *(const u16x8*)(base + INTER);
  float sum = 0.f;
  u16x8 ov;
#pragma unroll
  for (int j = 0; j < 8; ++j) {
    int c = c0 + j;
    float v = cw[c*3+0] * bf2f(xm[j]) + cw[c*3+1] * bf2f(x0[j]) + cw[c*3+2] * bf2f(xpv[j]) + cbias[c];
    float sg = v / (1.f + expf(-v));
    float o = sg + condv[b * INTER + c];
    sum += o;
    ov[j] = f2bf(o);
  }
  *(u16x8*)(xp + (size_t)r * INTER + c0) = ov;
  for (int o = 32; o; o >>= 1) sum += __shfl_xor(sum, o);
  __shared__ float ps[4];
  if ((threadIdx.x & 63) == 0) ps[threadIdx.x >> 6] = sum;
  __syncthreads();
  if (threadIdx.x == 0) xpsum[r] = ps[0] + ps[1] + ps[2] + ps[3];
}

__global__ __launch_bounds__(256) void scanprep_kernel(const float* __restrict__ A_log,
    const float* __restrict__ dtsum, const float* __restrict__ xpsum,
    const float* BmatIn, float* Adisc, float* Bx)
{
  int e = blockIdx.x * 256 + threadIdx.x;
  int r = e >> 6, s = e & 63;
  float dtm = dtsum[r] * (1.f / INTER);
  float xpm = xpsum[r] * (1.f / INTER);
  Adisc[e] = expf(-expf(A_log[s]) * dtm);
  Bx[e] = BmatIn[e] * dtm * xpm;
}

__global__ __launch_bounds__(64) void scanA_kernel(const float* __restrict__ Adisc,
    const float* __restrict__ Bx, float* __restrict__ cA, float* __restrict__ cB)
{
  int g = blockIdx.x; int b = g / NCH, ch = g % NCH;
  int s = threadIdx.x;
  float ap = 1.f, bacc = 0.f;
  size_t base = ((size_t)(b * LEN + ch * LC) << 6) + s;
  for (int i = 0; i < LC; ++i) {
    float a = Adisc[base], bb = Bx[base];
    bacc = fmaf(a, bacc, bb);
    ap *= a;
    base += 64;
  }
  cA[(size_t)g * 64 + s] = ap;
  cB[(size_t)g * 64 + s] = bacc;
}

__global__ __launch_bounds__(256) void scanB_kernel(const float* __restrict__ cA,
    const float* __restrict__ cB, float* __restrict__ hin)
{
  int t = threadIdx.x; int b = t >> 6, s = t & 63;
  float h = 0.f;
  for (int ch = 0; ch < NCH; ++ch) {
    size_t i = (size_t)(b * NCH + ch) * 64 + s;
    hin[i] = h;
    h = fmaf(cA[i], h, cB[i]);
  }
}

__global__ __launch_bounds__(64) void scanC_kernel(const float* __restrict__ Adisc,
    const float* __restrict__ Bx, const float* __restrict__ Cmat,
    const float* __restrict__ hin, float* __restrict__ yvec)
{
  int g = blockIdx.x; int b = g / NCH, ch = g % NCH;
  int s = threadIdx.x;
  float h = hin[(size_t)g * 64 + s];
  int l0 = ch * LC;
  size_t base = ((size_t)(b * LEN + l0) << 6) + s;
  for (int i = 0; i < LC; ++i) {
    h = fmaf(Adisc[base], h, Bx[base]);
    float p = Cmat[base] * h;
    for (int o = 32; o; o >>= 1) p += __shfl_xor(p, o);
    if (s == 0) yvec[b * LEN + l0 + i] = p;
    base += 64;
  }
}

__global__ __launch_bounds__(256) void yin_kernel(const u16* __restrict__ xp,
    const u16* __restrict__ gate, const float* __restrict__ yvec,
    const float* __restrict__ Dp, u16* __restrict__ yin)
{
  int i = blockIdx.x * 256 + threadIdx.x;
  int r = i >> 8;
  int c0 = (i & 255) * 8;
  size_t off = (size_t)r * INTER + c0;
  u16x8 xv = *(const u16x8*)(xp + off);
  u16x8 gv = *(const u16x8*)(gate + off);
  float yv = yvec[r];
  u16x8 ov;
#pragma unroll
  for (int j = 0; j < 8; ++j) {
    float g = bf2f(gv[j]);
    float sg = g / (1.f + expf(-g));
    float val = (yv + bf2f(xv[j]) * Dp[c0 + j]) * sg;
    ov[j] = f2bf(val);
  }
  *(u16x8*)(yin + off) = ov;
}

extern "C" void kernel_launch(void* const* d_in, const int* in_sizes, int n_in,
                              void* d_out, int out_size, void* d_ws, size_t ws_size,
                              hipStream_t stream) {
  (void)in_sizes; (void)n_in; (void)out_size; (void)ws_size;
  const float* x         = (const float*)d_in[0];
  const float* condition = (const float*)d_in[1];
  const float* ln_g      = (const float*)d_in[2];
  const float* ln_b      = (const float*)d_in[3];
  const float* W_in      = (const float*)d_in[4];
  const float* b_in      = (const float*)d_in[5];
  const float* conv_w    = (const float*)d_in[6];
  const float* conv_b    = (const float*)d_in[7];
  const float* W_dt      = (const float*)d_in[8];
  const float* b_dt      = (const float*)d_in[9];
  const float* dt_bias   = (const float*)d_in[10];
  const float* A_log     = (const float*)d_in[11];
  const float* Dp        = (const float*)d_in[12];
  const float* W_B       = (const float*)d_in[13];
  const float* b_B       = (const float*)d_in[14];
  const float* W_C       = (const float*)d_in[15];
  const float* b_C       = (const float*)d_in[16];
  const float* W_cond    = (const float*)d_in[17];
  const float* b_cond    = (const float*)d_in[18];
  const float* W_out     = (const float*)d_in[19];
  const float* b_out     = (const float*)d_in[20];

  char* ws = (char*)d_ws;
  u16*   wt_in  = (u16*)(ws + 0);            // [4096][1024] bf16
  u16*   wt_cat = (u16*)(ws + 8388608);      // [2176][2048] bf16
  u16*   wt_out = (u16*)(ws + 17301504);     // [1024][2048] bf16
  float* bcat   = (float*)(ws + 21495808);   // [2176]
  float* condv  = (float*)(ws + 21504512);   // [4][2048]
  float* dtsum  = (float*)(ws + 21537280);   // [16384]
  float* xpsum  = (float*)(ws + 21602816);   // [16384]
  float* yvec   = (float*)(ws + 21668352);   // [16384]
  float* cA     = (float*)(ws + 21733888);   // [128][64]
  float* cB     = (float*)(ws + 21766656);
  float* hin    = (float*)(ws + 21799424);
  u16*   xn     = (u16*)(ws + 21832192);     // [16384][1024] bf16 (dead after GEMM1)
  float* Bmat   = (float*)(ws + 21832192);   // aliases dead xn
  float* Cmat   = (float*)(ws + 21832192 + 4194304);
  float* Adisc  = (float*)(ws + 21832192 + 8388608);
  u16*   xproj  = (u16*)(ws + 55386624);     // [16384][2048] bf16 (reused as yin)
  u16*   gate   = (u16*)(ws + 122495488);    // [16384][2048] bf16
  u16*   xp     = (u16*)(ws + 189604352);    // [16384][2048] bf16

  hipMemsetAsync(dtsum, 0, RTOT * 4, stream);

  wconvT_kernel<<<dim3(NQK/32, HID/32), 256, 0, stream>>>(W_in, wt_in, HID, NQK);
  wconvT_kernel<<<dim3(INTER/32, INTER/32), 256, 0, stream>>>(W_dt, wt_cat, INTER, INTER);
  wconvT_kernel<<<dim3(STATE/32, INTER/32), 256, 0, stream>>>(W_B, wt_cat + (size_t)2048*2048, INTER, STATE);
  wconvT_kernel<<<dim3(STATE/32, INTER/32), 256, 0, stream>>>(W_C, wt_cat + (size_t)2112*2048, INTER, STATE);
  wconvT_kernel<<<dim3(HID/32, INTER/32), 256, 0, stream>>>(W_out, wt_out, INTER, HID);
  bcat_kernel<<<dim3(9), 256, 0, stream>>>(b_dt, dt_bias, b_B, b_C, bcat);
  cond_kernel<<<dim3(INTER/256, BSZ), 256, 0, stream>>>(condition, W_cond, b_cond, condv);
  ln_kernel<<<dim3(RTOT), 256, 0, stream>>>(x, ln_g, ln_b, xn);

  gemm256<0><<<dim3(NQK/256, RTOT/256), 512, 0, stream>>>(
      xn, wt_in, HID, b_in, xproj, gate, nullptr, nullptr, nullptr);

  conv_kernel<<<dim3(RTOT), 256, 0, stream>>>(xproj, conv_w, conv_b, condv, xp, xpsum);

  // dt part (cols 0..2047) on the 8-phase kernel
  gemm256<1><<<dim3(INTER/256, RTOT/256), 512, 0, stream>>>(
      xp, wt_cat, INTER, bcat, nullptr, nullptr, dtsum, nullptr, nullptr);
  // B/C part (128 cols) on the old 128^2 kernel
  gemm_bt<3><<<dim3(1, RTOT/128), 256, 0, stream>>>(
      xp, wt_cat + (size_t)2048*2048, INTER, bcat + INTER, Bmat, Cmat);

  scanprep_kernel<<<dim3(RTOT*STATE/256), 256, 0, stream>>>(A_log, dtsum, xpsum, Bmat, Adisc, Bmat);
  scanA_kernel<<<dim3(BSZ*NCH), 64, 0, stream>>>(Adisc, Bmat, cA, cB);
  scanB_kernel<<<dim3(1), 256, 0, stream>>>(cA, cB, hin);
  scanC_kernel<<<dim3(BSZ*NCH), 64, 0, stream>>>(Adisc, Bmat, Cmat, hin, yvec);

  yin_kernel<<<dim3(RTOT*INTER/8/256), 256, 0, stream>>>(xp, gate, yvec, Dp, xproj);

  gemm256<2><<<dim3(HID/256, RTOT/256), 512, 0, stream>>>(
      xproj, wt_out, INTER, b_out, nullptr, nullptr, nullptr, x, (float*)d_out);
}